// Round 1
// baseline (52.560 us; speedup 1.0000x reference)
//
#include <hip/hip_runtime.h>

// LightweightConv1d: x (T,B,C) f32, weight (H,1,K) f32 (softmax over K), bias (C) f32
// out[t,b,c] = bias[c] + sum_k softmax(w[h])[k] * x[t-P+k, b, c],  h = c / (C/H)
#define T_DIM 2048
#define B_DIM 32
#define C_DIM 512
#define H_DIM 16
#define K_DIM 31
#define P_PAD 15
#define SEG 16
#define SEGLEN (T_DIM / SEG)     // 128 time-steps per thread
#define TT 16                    // chunk of outputs per iteration
#define WIN (TT + K_DIM - 1)     // 46-element register sliding window
#define STRIDE (B_DIM * C_DIM)   // 16384 floats between consecutive t

__global__ __launch_bounds__(256, 4)
void lwconv_kernel(const float* __restrict__ x, const float* __restrict__ weight,
                   const float* __restrict__ bias, float* __restrict__ out)
{
    const int bid = blockIdx.x;
    const int c   = ((bid & 1) << 8) | threadIdx.x;   // lane -> consecutive c (coalesced)
    const int b   = (bid >> 1) & (B_DIM - 1);
    const int seg = bid >> 6;
    const int h   = c >> 5;                           // c / (C/H), R = 32

    // per-thread softmax of the 31 head weights (fp32, max-subtracted)
    float w[K_DIM];
    float m = -3.4e38f;
    #pragma unroll
    for (int k = 0; k < K_DIM; ++k) { w[k] = weight[h * K_DIM + k]; m = fmaxf(m, w[k]); }
    float s = 0.f;
    #pragma unroll
    for (int k = 0; k < K_DIM; ++k) { w[k] = __expf(w[k] - m); s += w[k]; }
    const float inv = 1.f / s;
    #pragma unroll
    for (int k = 0; k < K_DIM; ++k) w[k] *= inv;

    const float bv = bias[c];
    const float* xp = x + (size_t)b * C_DIM + c;
    float*       op = out + (size_t)b * C_DIM + c;
    const int t0 = seg * SEGLEN;

    // Preload left halo: xw[0..29] = x[t0-15 .. t0+14] (zero below t=0).
    // Upper bound never hit here: t0+14 <= 1934 < 2048.
    float xw[WIN];
    #pragma unroll
    for (int i = 0; i < K_DIM - 1; ++i) {
        int t = t0 - P_PAD + i;
        xw[i] = (t >= 0) ? xp[(size_t)t * STRIDE] : 0.f;
    }

    #pragma unroll 1   // keep the chunk loop rolled: small icache footprint, regs rotate via movs
    for (int chunk = 0; chunk < SEGLEN / TT; ++chunk) {
        const int tb = t0 + chunk * TT;   // outputs tb .. tb+TT-1
        // load leading edge: xw[30..45] = x[tb+15 .. tb+30] (zero past T)
        #pragma unroll
        for (int i = 0; i < TT; ++i) {
            int t = tb + P_PAD + i;
            xw[K_DIM - 1 + i] = (t < T_DIM) ? xp[(size_t)t * STRIDE] : 0.f;
        }
        // compute + store 16 outputs, all static indexing
        #pragma unroll
        for (int i = 0; i < TT; ++i) {
            float acc = bv;
            #pragma unroll
            for (int k = 0; k < K_DIM; ++k) acc = fmaf(w[k], xw[i + k], acc);
            op[(size_t)(tb + i) * STRIDE] = acc;
        }
        // shift window left by TT
        #pragma unroll
        for (int i = 0; i < K_DIM - 1; ++i) xw[i] = xw[i + TT];
    }
}

extern "C" void kernel_launch(void* const* d_in, const int* in_sizes, int n_in,
                              void* d_out, int out_size, void* d_ws, size_t ws_size,
                              hipStream_t stream) {
    const float* x      = (const float*)d_in[0];
    const float* weight = (const float*)d_in[1];
    const float* bias   = (const float*)d_in[2];
    float* out = (float*)d_out;
    dim3 grid(2 * B_DIM * SEG);   // c_hi(2) * b(32) * seg(16) = 1024 blocks
    dim3 block(256);
    lwconv_kernel<<<grid, block, 0, stream>>>(x, weight, bias, out);
}